// Round 8
// baseline (322.469 us; speedup 1.0000x reference)
//
#include <hip/hip_runtime.h>

#define NPAIR 8192   // B*NCG

// Fused single kernel, all fp32 (proven R5/R6). Tables computed redundantly
// per block into LDS. W2 staged into LDS in two 32KB halves so the gemm runs
// off the DS pipe (R5's global-W2 gemm was latency-bound at VALUBusy 23%).
// NO second __launch_bounds__ arg: on this toolchain (512,N) caps VGPRs at
// 256/N ((512,8)->32, (512,4)->64), causing the R6/R7 spill storms.
__global__ __launch_bounds__(512) void fused_kernel(
    const int*   __restrict__ archs,
    const float* __restrict__ init_emb, const float* __restrict__ other_emb,
    const float* __restrict__ op_embs,  const float* __restrict__ Wx,
    const float* __restrict__ bx,       const float* __restrict__ W1,
    const float* __restrict__ Wa1,      const float* __restrict__ ba1,
    const float* __restrict__ W2,       const float* __restrict__ Wa2,
    const float* __restrict__ ba2,      float* __restrict__ out)
{
  __shared__ float w2sh[8192];     // W2 half [64][128] (32KB); y0 overlaid
  __shared__ float s1sh[1536];     // support1 [2][6][128]
  __shared__ float at1sh[896];     // sigmoid attn L1 [7][128], row0 = 0
  __shared__ float at2sh[896];     // sigmoid attn L2 [7][128], row0 = 0
  __shared__ float s2ish[512];     // support2, init nodes [2*2][128]
  __shared__ float y1sh[8 * 512];  // relu(layer1) [8 pairs][4][128]
  // total 16128 floats = 64512 B <= 64 KB

  const int t = threadIdx.x;
  float* y0 = w2sh;                // overlay: y0 [2][6][48], dead after stage 2

  // ---- stage 1: y0 = node @ Wx + bx (576 outputs) ----
  for (int idx = t; idx < 576; idx += 512) {
    int c = idx / 288, i = (idx / 48) % 6, h = idx % 48;
    const float* nptr = (i < 2) ? (init_emb + (c * 2 + i) * 48)
                                : (other_emb + c * 48);
    float acc = bx[h];
    #pragma unroll
    for (int d = 0; d < 48; ++d) acc += nptr[d] * Wx[d * 48 + h];
    y0[idx] = acc;
  }
  // ---- stage 3: attn tables (896 outputs), NONE mask baked into row 0 ----
  for (int idx = t; idx < 896; idx += 512) {
    int op = idx >> 7, o = idx & 127;
    float a1 = ba1[o], a2 = ba2[o];
    #pragma unroll
    for (int d = 0; d < 48; ++d) {
      float e = op_embs[op * 48 + d];
      a1 += e * Wa1[d * 128 + o];
      a2 += e * Wa2[d * 128 + o];
    }
    bool z = (op == 0);
    at1sh[idx] = z ? 0.f : 1.f / (1.f + __expf(-a1));
    at2sh[idx] = z ? 0.f : 1.f / (1.f + __expf(-a2));
  }
  __syncthreads();

  // ---- stage 2: support1 = y0 @ W1 (1536 outputs) ----
  for (int idx = t; idx < 1536; idx += 512) {
    int ci = idx >> 7, o = idx & 127;
    const float* yp = y0 + ci * 48;
    float acc = 0.f;
    #pragma unroll
    for (int h = 0; h < 48; ++h) acc += yp[h] * W1[h * 128 + o];
    s1sh[idx] = acc;
  }
  __syncthreads();   // y0 dead from here; s1sh ready

  // ---- stage 4: support2 for init nodes (512 outputs, one per thread) ----
  {
    int c = t >> 8, i = (t >> 7) & 1, o = t & 127;
    const float* sp = s1sh + (c * 6 + i) * 128;
    float acc = 0.f;
    #pragma unroll
    for (int h = 0; h < 128; ++h) acc += fmaxf(sp[h], 0.f) * W2[h * 128 + o];
    s2ish[(c * 2 + i) * 128 + o] = acc;
  }

  // ---- layer 1: one (b,c) pair per wave ----
  const int w  = __builtin_amdgcn_readfirstlane(t >> 6);  // wave id
  const int o2 = t & 63;                 // channel pair 2*o2, 2*o2+1
  const int p  = blockIdx.x * 8 + w;     // global pair
  const int c  = p & 1;

  const int* ap = archs + p * 16;        // wave-uniform -> scalar loads
  int f[8], g[8];
  #pragma unroll
  for (int e = 0; e < 8; ++e) { f[e] = ap[e]; g[e] = ap[8 + e]; }

  const float2* s1f = (const float2*)s1sh;   // [12][64]
  const float2* a1f = (const float2*)at1sh;  // [7][64]
  const int cb = c * 384;
  float* yd = y1sh + w * 512;
  #pragma unroll
  for (int i = 0; i < 4; ++i) {
    float2 v  = s1f[cb + (2 + i) * 64 + o2];
    int e0 = 2 * i, e1 = 2 * i + 1;
    float2 A0 = a1f[g[e0] * 64 + o2];
    float2 B0 = s1f[cb + f[e0] * 64 + o2];
    float2 A1 = a1f[g[e1] * 64 + o2];
    float2 B1 = s1f[cb + f[e1] * 64 + o2];
    v.x += A0.x * B0.x + A1.x * B1.x;
    v.y += A0.y * B0.y + A1.y * B1.y;
    ((float2*)(yd + i * 128))[o2] = make_float2(fmaxf(v.x, 0.f), fmaxf(v.y, 0.f));
  }

  // ---- gemm: y1 (4x128) @ W2 (128x128), W2 via LDS in two halves ----
  const float* y1p = y1sh + w * 512;     // own-wave y1 (no barrier needed)
  float ax0 = 0, ax1 = 0, ax2 = 0, ax3 = 0;
  float ay0 = 0, ay1 = 0, ay2 = 0, ay3 = 0;

  #define COMP4(v, j) ((j) == 0 ? (v).x : (j) == 1 ? (v).y : (j) == 2 ? (v).z : (v).w)
  #pragma unroll
  for (int half = 0; half < 2; ++half) {
    __syncthreads();   // prior w2sh/y0 readers done
    #pragma unroll
    for (int k = 0; k < 4; ++k)        // stage 32KB: 4 float4 per thread
      ((float4*)w2sh)[t + k * 512] = ((const float4*)W2)[half * 2048 + t + k * 512];
    __syncthreads();   // w2sh staged

    const float2* w2f = (const float2*)w2sh;   // [64][64] float2
    const float*  yh  = y1p + half * 64;
    for (int h = 0; h < 64; h += 4) {
      float4 q0 = *(const float4*)(yh + 0 * 128 + h);  // wave-broadcast LDS
      float4 q1 = *(const float4*)(yh + 1 * 128 + h);
      float4 q2 = *(const float4*)(yh + 2 * 128 + h);
      float4 q3 = *(const float4*)(yh + 3 * 128 + h);
      #pragma unroll
      for (int j = 0; j < 4; ++j) {
        float2 wf = w2f[(h + j) * 64 + o2];
        float w0 = wf.x, w1 = wf.y, y;
        y = COMP4(q0, j); ax0 += y * w0; ay0 += y * w1;
        y = COMP4(q1, j); ax1 += y * w0; ay1 += y * w1;
        y = COMP4(q2, j); ax2 += y * w0; ay2 += y * w1;
        y = COMP4(q3, j); ax3 += y * w0; ay3 += y * w1;
      }
    }
  }

  // ---- layer-2 edge aggregation + mean over nodes 2..5 ----
  const float2* a2f = (const float2*)at2sh;   // [7][64]
  const float2* s2f = (const float2*)s2ish;   // [4][64]
  float2 S0 = s2f[(c * 2 + 0) * 64 + o2];
  float2 S1 = s2f[(c * 2 + 1) * 64 + o2];
  float r0 = ax0 + ax1 + ax2 + ax3;
  float r1 = ay0 + ay1 + ay2 + ay3;
  #pragma unroll
  for (int e = 0; e < 8; ++e) {
    float2 a = a2f[g[e] * 64 + o2];   // row 0 zero -> masks op==NONE
    int fe = f[e];
    float sx, sy;
    if (fe == 0)      { sx = S0.x; sy = S0.y; }
    else if (fe == 1) { sx = S1.x; sy = S1.y; }
    else if (fe == 2) { sx = ax0; sy = ay0; }
    else if (fe == 3) { sx = ax1; sy = ay1; }
    else if (fe == 4) { sx = ax2; sy = ay2; }
    else              { sx = ax3; sy = ay3; }
    r0 += a.x * sx;
    r1 += a.y * sy;
  }
  ((float2*)out)[p * 64 + o2] = make_float2(r0 * 0.25f, r1 * 0.25f);
}

extern "C" void kernel_launch(void* const* d_in, const int* in_sizes, int n_in,
                              void* d_out, int out_size, void* d_ws, size_t ws_size,
                              hipStream_t stream) {
  fused_kernel<<<NPAIR / 8, 512, 0, stream>>>(
      (const int*)d_in[0],
      (const float*)d_in[1], (const float*)d_in[2], (const float*)d_in[3],
      (const float*)d_in[4], (const float*)d_in[5], (const float*)d_in[6],
      (const float*)d_in[7], (const float*)d_in[8], (const float*)d_in[9],
      (const float*)d_in[10], (const float*)d_in[11], (float*)d_out);
}

// Round 9
// 121.335 us; speedup vs baseline: 2.6577x; 2.6577x over previous
//
#include <hip/hip_runtime.h>

#define NPAIR 8192   // B*NCG

// ws float layout (all fp32)
#define WS_S1   0      // support1 [2][6][128]
#define WS_AT1  1536   // attn table layer1 [7][128] (row 0 zeroed = NONE mask)
#define WS_AT2  2432   // attn table layer2 [7][128]
#define WS_S2I  3328   // support2 for init nodes [2][2][128]

__device__ __forceinline__ float sigmoidf_(float x) {
  return 1.0f / (1.0f + __expf(-x));
}

// ---------------- Phase A: batch-independent tables (R6-verbatim, clean) ----
__global__ __launch_bounds__(512) void precompute_kernel(
    const float* __restrict__ init_emb, const float* __restrict__ other_emb,
    const float* __restrict__ op_embs,  const float* __restrict__ Wx,
    const float* __restrict__ bx,       const float* __restrict__ W1,
    const float* __restrict__ Wa1,      const float* __restrict__ ba1,
    const float* __restrict__ W2,       const float* __restrict__ Wa2,
    const float* __restrict__ ba2,      float* __restrict__ ws)
{
  const int t   = threadIdx.x;
  const int blk = blockIdx.x;   // 0..7

  __shared__ float y0[2 * 6 * 48];     // node @ Wx + bx
  __shared__ float s1sh[2 * 6 * 128];  // support1

  // stage 1: y0[c][i][h] = node @ Wx + bx
  for (int idx = t; idx < 2 * 6 * 48; idx += 512) {
    int c = idx / 288, i = (idx / 48) % 6, h = idx % 48;
    const float* nptr = (i < 2) ? (init_emb + (c * 2 + i) * 48)
                                : (other_emb + c * 48);
    float acc = bx[h];
    for (int d = 0; d < 48; ++d)
      acc += nptr[d] * Wx[d * 48 + h];
    y0[idx] = acc;
  }
  __syncthreads();

  // stage 2: support1 (all blocks; duplicate same-value ws writes are benign)
  for (int idx = t; idx < 2 * 6 * 128; idx += 512) {
    int ci = idx >> 7, o = idx & 127;
    const float* yp = y0 + ci * 48;
    float acc = 0.f;
    for (int h = 0; h < 48; ++h) acc += yp[h] * W1[h * 128 + o];
    s1sh[idx] = acc;
    ws[WS_S1 + idx] = acc;
  }

  // stage 3: attn tables — sliced via loop bounds: [blk*112, (blk+1)*112)
  for (int idx = blk * 112 + t; idx < (blk + 1) * 112; idx += 512) {
    int op = idx >> 7, o = idx & 127;
    float a1 = ba1[o], a2 = ba2[o];
    for (int d = 0; d < 48; ++d) {
      float e = op_embs[op * 48 + d];
      a1 += e * Wa1[d * 128 + o];
      a2 += e * Wa2[d * 128 + o];
    }
    ws[WS_AT1 + idx] = (op == 0) ? 0.f : sigmoidf_(a1);  // NONE mask baked in
    ws[WS_AT2 + idx] = (op == 0) ? 0.f : sigmoidf_(a2);
  }
  __syncthreads();

  // stage 4: support2 for init nodes — sliced: [blk*64, (blk+1)*64)
  for (int idx = blk * 64 + t; idx < (blk + 1) * 64; idx += 512) {
    int c = idx >> 8, i = (idx >> 7) & 1, o = idx & 127;
    const float* sp = s1sh + (c * 6 + i) * 128;
    float acc = 0.f;
    for (int h = 0; h < 128; ++h)
      acc += fmaxf(sp[h], 0.f) * W2[h * 128 + o];
    ws[WS_S2I + idx] = acc;
  }
}

// ---------------- Phase B: R5-main structure + W2 staged through LDS --------
// R5 measured VALUBusy 23%: the gemm was latency-bound on the global W2
// stream (64KB > 32KB L1 -> every pass L1-misses to ~200cyc L2). Staging W2
// into LDS in two 32KB halves feeds the gemm from the DS pipe instead.
// Everything else is R5-verbatim (256 thr, archsh, plain launch_bounds(256)
// -- VGPR 56, zero spill). W2 LDS reads: lane-consecutive float2 = 2-way
// bank conflict = free (m136); y1 reads are wave-broadcast = free.
#define COMP4(v, j) ((j) == 0 ? (v).x : (j) == 1 ? (v).y : (j) == 2 ? (v).z : (v).w)

__global__ __launch_bounds__(256) void main_kernel(
    const int* __restrict__ archs, const float* __restrict__ W2,
    const float* __restrict__ ws, float* __restrict__ out)
{
  const int t  = threadIdx.x;
  const int pp = t >> 6;          // pair slot in block (== wave id)
  const int o2 = t & 63;          // channel pair: channels 2*o2, 2*o2+1
  const int P  = blockIdx.x * 4 + pp;   // global (b,c) pair
  const int c  = P & 1;

  __shared__ float w2sh[8192];    // one 32KB half of W2: [64 rows][128 ch]
  __shared__ float y1sh[4][512];  // [pair][node 2..5][128]
  __shared__ int   archsh[64];
  if (t < 64) archsh[t] = archs[blockIdx.x * 64 + t];
  __syncthreads();

  int f[8], op[8];
  #pragma unroll
  for (int e = 0; e < 8; ++e) { f[e] = archsh[pp * 16 + e]; op[e] = archsh[pp * 16 + 8 + e]; }

  const float2* s1p = (const float2*)ws + c * 384;      // support1[c] [6][64]f2
  const float2* at1 = (const float2*)(ws + WS_AT1);     // [7][64] f2
  const float2* at2 = (const float2*)(ws + WS_AT2);
  const float2* s2i = (const float2*)(ws + WS_S2I) + c * 128;

  // pre-issue epilogue table loads (latency hidden behind the gemm)
  float2 A2[8];
  #pragma unroll
  for (int e = 0; e < 8; ++e) A2[e] = at2[op[e] * 64 + o2];
  float2 S0 = s2i[o2], S1 = s2i[64 + o2];

  // layer 1 for nodes 2..5 (attn row 0 is zero -> branchless mask)
  #pragma unroll
  for (int i = 0; i < 4; ++i) {
    float2 v = s1p[(2 + i) * 64 + o2];
    int e0 = 2 * i, e1 = 2 * i + 1;
    float2 A0 = at1[op[e0] * 64 + o2];
    float2 B0 = s1p[f[e0] * 64 + o2];
    float2 A1 = at1[op[e1] * 64 + o2];
    float2 B1 = s1p[f[e1] * 64 + o2];
    v.x += A0.x * B0.x + A1.x * B1.x;
    v.y += A0.y * B0.y + A1.y * B1.y;
    ((float2*)(y1sh[pp] + i * 128))[o2] =
        make_float2(fmaxf(v.x, 0.f), fmaxf(v.y, 0.f));
  }

  // gemm: y1 (4x128) @ W2 (128x128); W2 via LDS, two 32KB halves
  const float* y1p = y1sh[pp];
  float ax0 = 0, ax1 = 0, ax2 = 0, ax3 = 0;
  float ay0 = 0, ay1 = 0, ay2 = 0, ay3 = 0;

  for (int half = 0; half < 2; ++half) {
    __syncthreads();   // half 0: y1sh/archsh settled; half 1: w2sh readers done
    #pragma unroll
    for (int k = 0; k < 8; ++k)   // stage 32KB: 8 float4 per thread, coalesced
      ((float4*)w2sh)[t + k * 256] = ((const float4*)W2)[half * 2048 + t + k * 256];
    __syncthreads();   // w2sh staged

    const float2* w2f = (const float2*)w2sh;   // [64 rows][64 ch-pairs]
    const float*  yh  = y1p + half * 64;
    for (int h = 0; h < 64; h += 4) {
      float4 q0 = *(const float4*)(yh + 0 * 128 + h);  // wave-broadcast LDS
      float4 q1 = *(const float4*)(yh + 1 * 128 + h);
      float4 q2 = *(const float4*)(yh + 2 * 128 + h);
      float4 q3 = *(const float4*)(yh + 3 * 128 + h);
      #pragma unroll
      for (int j = 0; j < 4; ++j) {
        float2 wf = w2f[(h + j) * 64 + o2];
        float w0 = wf.x, w1 = wf.y, y;
        y = COMP4(q0, j); ax0 += y * w0; ay0 += y * w1;
        y = COMP4(q1, j); ax1 += y * w0; ay1 += y * w1;
        y = COMP4(q2, j); ax2 += y * w0; ay2 += y * w1;
        y = COMP4(q3, j); ax3 += y * w0; ay3 += y * w1;
      }
    }
  }

  // layer-2 edge aggregation + mean over nodes 2..5 (R5 verbatim)
  float r0 = ax0 + ax1 + ax2 + ax3;
  float r1 = ay0 + ay1 + ay2 + ay3;
  #pragma unroll
  for (int e = 0; e < 8; ++e) {
    int fe = f[e];
    float sx, sy;
    if (fe == 0)      { sx = S0.x; sy = S0.y; }
    else if (fe == 1) { sx = S1.x; sy = S1.y; }
    else if (fe == 2) { sx = ax0; sy = ay0; }
    else if (fe == 3) { sx = ax1; sy = ay1; }
    else if (fe == 4) { sx = ax2; sy = ay2; }
    else              { sx = ax3; sy = ay3; }
    r0 += A2[e].x * sx;
    r1 += A2[e].y * sy;
  }
  r0 *= 0.25f; r1 *= 0.25f;

  ((float2*)out)[P * 64 + o2] = make_float2(r0, r1);
}

extern "C" void kernel_launch(void* const* d_in, const int* in_sizes, int n_in,
                              void* d_out, int out_size, void* d_ws, size_t ws_size,
                              hipStream_t stream) {
  const int* archs = (const int*)d_in[0];
  float* ws = (float*)d_ws;
  precompute_kernel<<<8, 512, 0, stream>>>(
      (const float*)d_in[1], (const float*)d_in[2], (const float*)d_in[3],
      (const float*)d_in[4], (const float*)d_in[5], (const float*)d_in[6],
      (const float*)d_in[7], (const float*)d_in[8], (const float*)d_in[9],
      (const float*)d_in[10], (const float*)d_in[11], ws);
  main_kernel<<<NPAIR / 4, 256, 0, stream>>>(archs, (const float*)d_in[9], ws,
                                             (float*)d_out);
}

// Round 10
// 106.008 us; speedup vs baseline: 3.0419x; 1.1446x over previous
//
#include <hip/hip_runtime.h>

#define NPAIR 8192   // B*NCG

// ===================== NEW PATH: config-deduplicated =====================
// A step-node's layer-1 output depends only on (c, i, f_s0, op_s0, f_s1,
// op_s1); with f < i there are only 5292 distinct configs (+4 init rows).
// K1 builds support2 rows for every config (87 M MAC, W2 read 83x not
// 8192x); K2 is a pure gather/aggregate. R9 evidence: per-pair W2
// streaming (512 MB aggregate) was the invariant cost (R5 44us == R9
// 42us); dedup removes it structurally.
#define NCFG_REAL 5292
#define NCFG      5296      // + 4 pseudo-configs: init nodes [c][i]
#define CPER      2646      // configs per c
#define WS_AT2F   0         // at2 table [7][128] in ws (row 0 zeroed)
#define WS_TAB    1024      // tab [NCFG][128]
#define WS_NEED   ((size_t)(1024 + NCFG * 128) * 4)

#define COMP4(v, j) ((j) == 0 ? (v).x : (j) == 1 ? (v).y : (j) == 2 ? (v).z : (v).w)

__device__ __forceinline__ float sigmoidf_(float x) {
  return 1.0f / (1.0f + __expf(-x));
}

__global__ __launch_bounds__(512) void config_kernel(
    const float* __restrict__ init_emb, const float* __restrict__ other_emb,
    const float* __restrict__ op_embs,  const float* __restrict__ Wx,
    const float* __restrict__ bx,       const float* __restrict__ W1,
    const float* __restrict__ Wa1,      const float* __restrict__ ba1,
    const float* __restrict__ W2,       const float* __restrict__ Wa2,
    const float* __restrict__ ba2,      float* __restrict__ ws)
{
  __shared__ float y0[576];       // [2][6][48]
  __shared__ float s1sh[1536];    // support1 [2][6][128]
  __shared__ float at1sh[896];    // [7][128], row 0 zeroed
  __shared__ float at2sh[896];
  __shared__ float y1sh[8192];    // [8 waves][8 cfgs][128]  (32 KB)
  const int t = threadIdx.x;

  // ---- table phase (R8/R9-proven bodies, redundant per block) ----
  for (int idx = t; idx < 576; idx += 512) {
    int c = idx / 288, i = (idx / 48) % 6, h = idx % 48;
    const float* nptr = (i < 2) ? (init_emb + (c * 2 + i) * 48)
                                : (other_emb + c * 48);
    float acc = bx[h];
    for (int d = 0; d < 48; ++d) acc += nptr[d] * Wx[d * 48 + h];
    y0[idx] = acc;
  }
  for (int idx = t; idx < 896; idx += 512) {
    int op = idx >> 7, o = idx & 127;
    float a1 = ba1[o], a2 = ba2[o];
    for (int d = 0; d < 48; ++d) {
      float e = op_embs[op * 48 + d];
      a1 += e * Wa1[d * 128 + o];
      a2 += e * Wa2[d * 128 + o];
    }
    float v1 = (op == 0) ? 0.f : sigmoidf_(a1);   // NONE mask baked in
    float v2 = (op == 0) ? 0.f : sigmoidf_(a2);
    at1sh[idx] = v1;
    at2sh[idx] = v2;
    ws[WS_AT2F + idx] = v2;    // all blocks write identical values: benign
  }
  __syncthreads();
  for (int idx = t; idx < 1536; idx += 512) {
    int ci = idx >> 7, o = idx & 127;
    const float* yp = y0 + ci * 48;
    float acc = 0.f;
    for (int h = 0; h < 48; ++h) acc += yp[h] * W1[h * 128 + o];
    s1sh[idx] = acc;
  }
  __syncthreads();

  // ---- per-wave: 8 configs -> relu(y1_cfg) into LDS ----
  const int w  = t >> 6, o2 = t & 63;
  const int cfg0 = (blockIdx.x * 8 + w) * 8;
  const float2* s1f = (const float2*)s1sh;    // [12][64]
  const float2* a1f = (const float2*)at1sh;   // [7][64]

  #pragma unroll
  for (int r = 0; r < 8; ++r) {
    int cfg = cfg0 + r;
    if (cfg >= NCFG) continue;
    float2 v;
    if (cfg < NCFG_REAL) {
      int c = cfg / CPER, q = cfg % CPER;
      int i, b;
      if (q < 196)       { i = 2; b = 0; }
      else if (q < 637)  { i = 3; b = 196; }
      else if (q < 1421) { i = 4; b = 637; }
      else               { i = 5; b = 1421; }
      q -= b;
      int op2_ = q % 7; q /= 7;
      int f2_  = q % i; q /= i;
      int op1_ = q % 7;
      int f1_  = q / 7;
      int cb = c * 384;
      v = s1f[cb + i * 64 + o2];
      float2 A0 = a1f[op1_ * 64 + o2], B0 = s1f[cb + f1_ * 64 + o2];
      float2 A1 = a1f[op2_ * 64 + o2], B1 = s1f[cb + f2_ * 64 + o2];
      v.x += A0.x * B0.x + A1.x * B1.x;
      v.y += A0.y * B0.y + A1.y * B1.y;
    } else {                       // pseudo-config: init node (no in-edges)
      int j = cfg - NCFG_REAL, c = j >> 1, i = j & 1;
      v = s1f[c * 384 + i * 64 + o2];
    }
    ((float2*)(y1sh + (w * 8 + r) * 128))[o2] =
        make_float2(fmaxf(v.x, 0.f), fmaxf(v.y, 0.f));
  }
  __syncthreads();

  // ---- matvec: tab[cfg] = y1_cfg @ W2; one W2 float2 feeds 16 FMA ----
  const float* yb = y1sh + (w * 8) * 128;
  const float2* W2f = (const float2*)W2;
  float2 acc[8];
  #pragma unroll
  for (int r = 0; r < 8; ++r) acc[r] = make_float2(0.f, 0.f);

  for (int k = 0; k < 128; k += 4) {
    float4 yv[8];
    #pragma unroll
    for (int r = 0; r < 8; ++r)
      yv[r] = *(const float4*)(yb + r * 128 + k);   // LDS broadcast b128
    #pragma unroll
    for (int j = 0; j < 4; ++j) {
      float2 wv = W2f[(k + j) * 64 + o2];           // shared stream: L1-hot
      #pragma unroll
      for (int r = 0; r < 8; ++r) {
        float y = COMP4(yv[r], j);
        acc[r].x += y * wv.x;
        acc[r].y += y * wv.y;
      }
    }
  }

  float2* tab = (float2*)(ws + WS_TAB);
  #pragma unroll
  for (int r = 0; r < 8; ++r) {
    int cfg = cfg0 + r;
    if (cfg < NCFG) tab[cfg * 64 + o2] = acc[r];
  }
}

__global__ __launch_bounds__(256) void gather_kernel(
    const int* __restrict__ archs, const float* __restrict__ ws,
    float* __restrict__ out)
{
  const int t  = threadIdx.x;
  const int pp = t >> 6;
  const int o2 = t & 63;
  const int P  = blockIdx.x * 4 + pp;
  const int c  = P & 1;

  __shared__ int archsh[64];
  if (t < 64) archsh[t] = archs[blockIdx.x * 64 + t];
  __syncthreads();

  int f[8], op[8];
  #pragma unroll
  for (int e = 0; e < 8; ++e) { f[e] = archsh[pp * 16 + e]; op[e] = archsh[pp * 16 + 8 + e]; }

  const float2* tab = (const float2*)(ws + WS_TAB);
  const float2* a2f = (const float2*)(ws + WS_AT2F);

  // support2 rows for all 6 nodes of this pair
  float2 S0 = tab[(NCFG_REAL + c * 2 + 0) * 64 + o2];
  float2 S1 = tab[(NCFG_REAL + c * 2 + 1) * 64 + o2];
  float2 S2, S3, S4, S5;
  {
    const int ib[4] = {0, 196, 637, 1421};
    #pragma unroll
    for (int i = 2; i < 6; ++i) {
      int e0 = 2 * (i - 2), e1 = e0 + 1;
      int cid = c * CPER + ib[i - 2] +
                ((f[e0] * 7 + op[e0]) * i + f[e1]) * 7 + op[e1];
      float2 v = tab[cid * 64 + o2];
      if (i == 2) S2 = v; else if (i == 3) S3 = v;
      else if (i == 4) S4 = v; else S5 = v;
    }
  }
  float2 A2[8];
  #pragma unroll
  for (int e = 0; e < 8; ++e) A2[e] = a2f[op[e] * 64 + o2];

  float r0 = S2.x + S3.x + S4.x + S5.x;
  float r1 = S2.y + S3.y + S4.y + S5.y;
  #pragma unroll
  for (int e = 0; e < 8; ++e) {
    int fe = f[e];                 // fe < target node index <= 5 -> 0..4
    float sx, sy;
    if (fe == 0)      { sx = S0.x; sy = S0.y; }
    else if (fe == 1) { sx = S1.x; sy = S1.y; }
    else if (fe == 2) { sx = S2.x; sy = S2.y; }
    else if (fe == 3) { sx = S3.x; sy = S3.y; }
    else              { sx = S4.x; sy = S4.y; }
    r0 += A2[e].x * sx;
    r1 += A2[e].y * sy;
  }
  ((float2*)out)[P * 64 + o2] = make_float2(r0 * 0.25f, r1 * 0.25f);
}

// ===================== FALLBACK: R9 verbatim (if ws too small) ============
#define FB_S1   0
#define FB_AT1  1536
#define FB_AT2  2432
#define FB_S2I  3328

__global__ __launch_bounds__(512) void precompute_kernel(
    const float* __restrict__ init_emb, const float* __restrict__ other_emb,
    const float* __restrict__ op_embs,  const float* __restrict__ Wx,
    const float* __restrict__ bx,       const float* __restrict__ W1,
    const float* __restrict__ Wa1,      const float* __restrict__ ba1,
    const float* __restrict__ W2,       const float* __restrict__ Wa2,
    const float* __restrict__ ba2,      float* __restrict__ ws)
{
  const int t   = threadIdx.x;
  const int blk = blockIdx.x;
  __shared__ float y0[576];
  __shared__ float s1sh[1536];
  for (int idx = t; idx < 576; idx += 512) {
    int c = idx / 288, i = (idx / 48) % 6, h = idx % 48;
    const float* nptr = (i < 2) ? (init_emb + (c * 2 + i) * 48)
                                : (other_emb + c * 48);
    float acc = bx[h];
    for (int d = 0; d < 48; ++d) acc += nptr[d] * Wx[d * 48 + h];
    y0[idx] = acc;
  }
  __syncthreads();
  for (int idx = t; idx < 1536; idx += 512) {
    int ci = idx >> 7, o = idx & 127;
    const float* yp = y0 + ci * 48;
    float acc = 0.f;
    for (int h = 0; h < 48; ++h) acc += yp[h] * W1[h * 128 + o];
    s1sh[idx] = acc;
    ws[FB_S1 + idx] = acc;
  }
  for (int idx = blk * 112 + t; idx < (blk + 1) * 112; idx += 512) {
    int op = idx >> 7, o = idx & 127;
    float a1 = ba1[o], a2 = ba2[o];
    for (int d = 0; d < 48; ++d) {
      float e = op_embs[op * 48 + d];
      a1 += e * Wa1[d * 128 + o];
      a2 += e * Wa2[d * 128 + o];
    }
    ws[FB_AT1 + idx] = (op == 0) ? 0.f : sigmoidf_(a1);
    ws[FB_AT2 + idx] = (op == 0) ? 0.f : sigmoidf_(a2);
  }
  __syncthreads();
  for (int idx = blk * 64 + t; idx < (blk + 1) * 64; idx += 512) {
    int c = idx >> 8, i = (idx >> 7) & 1, o = idx & 127;
    const float* sp = s1sh + (c * 6 + i) * 128;
    float acc = 0.f;
    for (int h = 0; h < 128; ++h) acc += fmaxf(sp[h], 0.f) * W2[h * 128 + o];
    ws[FB_S2I + idx] = acc;
  }
}

__global__ __launch_bounds__(256) void main_kernel(
    const int* __restrict__ archs, const float* __restrict__ W2,
    const float* __restrict__ ws, float* __restrict__ out)
{
  const int t  = threadIdx.x;
  const int pp = t >> 6;
  const int o2 = t & 63;
  const int P  = blockIdx.x * 4 + pp;
  const int c  = P & 1;
  __shared__ float y1sh[4][512];
  __shared__ int   archsh[64];
  if (t < 64) archsh[t] = archs[blockIdx.x * 64 + t];
  __syncthreads();
  int f[8], op[8];
  #pragma unroll
  for (int e = 0; e < 8; ++e) { f[e] = archsh[pp * 16 + e]; op[e] = archsh[pp * 16 + 8 + e]; }
  const float2* s1p = (const float2*)ws + c * 384;
  const float2* at1 = (const float2*)(ws + FB_AT1);
  const float2* at2 = (const float2*)(ws + FB_AT2);
  const float2* s2i = (const float2*)(ws + FB_S2I) + c * 128;
  float2 A2[8];
  #pragma unroll
  for (int e = 0; e < 8; ++e) A2[e] = at2[op[e] * 64 + o2];
  float2 S0 = s2i[o2], S1 = s2i[64 + o2];
  #pragma unroll
  for (int i = 0; i < 4; ++i) {
    float2 v = s1p[(2 + i) * 64 + o2];
    int e0 = 2 * i, e1 = 2 * i + 1;
    float2 A0 = at1[op[e0] * 64 + o2];
    float2 B0 = s1p[f[e0] * 64 + o2];
    float2 A1 = at1[op[e1] * 64 + o2];
    float2 B1 = s1p[f[e1] * 64 + o2];
    v.x += A0.x * B0.x + A1.x * B1.x;
    v.y += A0.y * B0.y + A1.y * B1.y;
    ((float2*)(y1sh[pp] + i * 128))[o2] =
        make_float2(fmaxf(v.x, 0.f), fmaxf(v.y, 0.f));
  }
  __syncthreads();
  const float* y1p = y1sh[pp];
  const float2* W2f = (const float2*)W2;
  float ax0 = 0, ax1 = 0, ax2 = 0, ax3 = 0;
  float ay0 = 0, ay1 = 0, ay2 = 0, ay3 = 0;
  for (int h = 0; h < 128; h += 4) {
    float4 q0 = *(const float4*)(y1p + 0 * 128 + h);
    float4 q1 = *(const float4*)(y1p + 1 * 128 + h);
    float4 q2 = *(const float4*)(y1p + 2 * 128 + h);
    float4 q3 = *(const float4*)(y1p + 3 * 128 + h);
    #pragma unroll
    for (int j = 0; j < 4; ++j) {
      float2 wf = W2f[(h + j) * 64 + o2];
      float w0 = wf.x, w1 = wf.y, y;
      y = COMP4(q0, j); ax0 += y * w0; ay0 += y * w1;
      y = COMP4(q1, j); ax1 += y * w0; ay1 += y * w1;
      y = COMP4(q2, j); ax2 += y * w0; ay2 += y * w1;
      y = COMP4(q3, j); ax3 += y * w0; ay3 += y * w1;
    }
  }
  float r0 = ax0 + ax1 + ax2 + ax3;
  float r1 = ay0 + ay1 + ay2 + ay3;
  #pragma unroll
  for (int e = 0; e < 8; ++e) {
    int fe = f[e];
    float sx, sy;
    if (fe == 0)      { sx = S0.x; sy = S0.y; }
    else if (fe == 1) { sx = S1.x; sy = S1.y; }
    else if (fe == 2) { sx = ax0; sy = ay0; }
    else if (fe == 3) { sx = ax1; sy = ay1; }
    else if (fe == 4) { sx = ax2; sy = ay2; }
    else              { sx = ax3; sy = ay3; }
    r0 += A2[e].x * sx;
    r1 += A2[e].y * sy;
  }
  ((float2*)out)[P * 64 + o2] = make_float2(r0 * 0.25f, r1 * 0.25f);
}

extern "C" void kernel_launch(void* const* d_in, const int* in_sizes, int n_in,
                              void* d_out, int out_size, void* d_ws, size_t ws_size,
                              hipStream_t stream) {
  const int* archs = (const int*)d_in[0];
  float* ws = (float*)d_ws;
  if (ws_size >= WS_NEED) {
    config_kernel<<<83, 512, 0, stream>>>(
        (const float*)d_in[1], (const float*)d_in[2], (const float*)d_in[3],
        (const float*)d_in[4], (const float*)d_in[5], (const float*)d_in[6],
        (const float*)d_in[7], (const float*)d_in[8], (const float*)d_in[9],
        (const float*)d_in[10], (const float*)d_in[11], ws);
    gather_kernel<<<NPAIR / 4, 256, 0, stream>>>(archs, ws, (float*)d_out);
  } else {
    precompute_kernel<<<8, 512, 0, stream>>>(
        (const float*)d_in[1], (const float*)d_in[2], (const float*)d_in[3],
        (const float*)d_in[4], (const float*)d_in[5], (const float*)d_in[6],
        (const float*)d_in[7], (const float*)d_in[8], (const float*)d_in[9],
        (const float*)d_in[10], (const float*)d_in[11], ws);
    main_kernel<<<NPAIR / 4, 256, 0, stream>>>(archs, (const float*)d_in[9], ws,
                                               (float*)d_out);
  }
}

// Round 11
// 103.602 us; speedup vs baseline: 3.1126x; 1.0232x over previous
//
#include <hip/hip_runtime.h>

#define NPAIR 8192   // B*NCG

// ===================== config-deduplicated path =====================
// Node layer-1 output depends only on (c, i, f_s0, op_s0, f_s1, op_s1):
// 5292 real configs + 4 init pseudo-rows. K1 builds tab[cfg] = relu(y1)@W2
// (R10: cut total W2 traffic 100x, 121->106us). R11 change: K1's table
// phase stages weights into LDS via coalesced float4 (sequential 24KB
// overlays) -- the scalar-global-load table phase was the remaining ~20us.
#define NCFG_REAL 5292
#define NCFG      5296
#define CPER      2646
#define WS_AT2F   0         // at2 table [7][128] (row 0 zeroed)
#define WS_TAB    1024      // tab [NCFG][128]
#define WS_NEED   ((size_t)(1024 + NCFG * 128) * 4)

#define COMP4(v, j) ((j) == 0 ? (v).x : (j) == 1 ? (v).y : (j) == 2 ? (v).z : (v).w)

__device__ __forceinline__ float sigmoidf_(float x) {
  return 1.0f / (1.0f + __expf(-x));
}

__global__ __launch_bounds__(512) void config_kernel(
    const float* __restrict__ init_emb, const float* __restrict__ other_emb,
    const float* __restrict__ op_embs,  const float* __restrict__ Wx,
    const float* __restrict__ bx,       const float* __restrict__ W1,
    const float* __restrict__ Wa1,      const float* __restrict__ ba1,
    const float* __restrict__ W2,       const float* __restrict__ Wa2,
    const float* __restrict__ ba2,      float* __restrict__ ws)
{
  __shared__ __align__(16) float wsh[8192];   // weight staging, then y1 store
  __shared__ __align__(16) float s1sh[1536];  // support1 [2][6][128]
  __shared__ __align__(16) float at1sh[896];  // [7][128] row0=0
  __shared__ __align__(16) float at2sh[896];  // embeddings scratch, then at2
  __shared__ __align__(16) float y0[576];     // y0, then op_embs scratch
  const int t = threadIdx.x;

  // ---- step 1: stage Wx (2304 f) -> wsh; embeddings (336 f) -> at2sh ----
  for (int i = t; i < 576; i += 512) ((float4*)wsh)[i] = ((const float4*)Wx)[i];
  if (t < 48)       ((float4*)at2sh)[t] = ((const float4*)init_emb)[t];
  else if (t < 72)  ((float4*)at2sh)[t] = ((const float4*)other_emb)[t - 48];
  else if (t < 84)  ((float4*)at2sh)[t] = ((const float4*)bx)[t - 72];
  __syncthreads();

  // ---- step 2: y0[c][i][h] = node @ Wx + bx (all LDS operands) ----
  for (int idx = t; idx < 576; idx += 512) {
    int c = idx / 288, i = (idx / 48) % 6, h = idx % 48;
    const float* nptr = (i < 2) ? (at2sh + (c * 2 + i) * 48)
                                : (at2sh + 192 + c * 48);
    float acc = at2sh[288 + h];
    for (int d = 0; d < 48; ++d) acc += nptr[d] * wsh[d * 48 + h];
    y0[idx] = acc;
  }
  __syncthreads();

  // ---- step 3: stage W1 (6144 f) -> wsh; s1 = y0 @ W1 ----
  for (int i = t; i < 1536; i += 512) ((float4*)wsh)[i] = ((const float4*)W1)[i];
  __syncthreads();
  for (int idx = t; idx < 1536; idx += 512) {
    int ci = idx >> 7, o = idx & 127;
    const float* yp = y0 + ci * 48;
    float acc = 0.f;
    for (int h = 0; h < 48; ++h) acc += yp[h] * wsh[h * 128 + o];
    s1sh[idx] = acc;
  }
  __syncthreads();   // y0 free, W1 readers done

  // ---- step 4: stage Wa1 -> wsh, op_embs (336 f) -> y0; a1 raw -> at1sh ---
  for (int i = t; i < 1536; i += 512) ((float4*)wsh)[i] = ((const float4*)Wa1)[i];
  if (t < 84) ((float4*)y0)[t] = ((const float4*)op_embs)[t];
  __syncthreads();
  for (int idx = t; idx < 896; idx += 512) {
    int op = idx >> 7, o = idx & 127;
    float a = ba1[o];
    for (int d = 0; d < 48; ++d) a += y0[op * 48 + d] * wsh[d * 128 + o];
    at1sh[idx] = a;                    // raw; sigmoid in step 5
  }
  __syncthreads();

  // ---- step 5: stage Wa2 -> wsh; a2, sigmoid both, finalize tables ----
  for (int i = t; i < 1536; i += 512) ((float4*)wsh)[i] = ((const float4*)Wa2)[i];
  __syncthreads();
  for (int idx = t; idx < 896; idx += 512) {
    int op = idx >> 7, o = idx & 127;
    float a2 = ba2[o];
    for (int d = 0; d < 48; ++d) a2 += y0[op * 48 + d] * wsh[d * 128 + o];
    float v1 = (op == 0) ? 0.f : sigmoidf_(at1sh[idx]);   // NONE mask baked in
    float v2 = (op == 0) ? 0.f : sigmoidf_(a2);
    at1sh[idx] = v1;
    at2sh[idx] = v2;                   // overwrites embedding scratch (dead)
    ws[WS_AT2F + idx] = v2;            // identical from all blocks: benign
  }
  __syncthreads();

  // ---- step 6: per-wave 8 configs -> relu(y1) into wsh (R10 verbatim) ----
  const int w  = t >> 6, o2 = t & 63;
  const int cfg0 = (blockIdx.x * 8 + w) * 8;
  const float2* s1f = (const float2*)s1sh;    // [12][64]
  const float2* a1f = (const float2*)at1sh;   // [7][64]

  #pragma unroll
  for (int r = 0; r < 8; ++r) {
    int cfg = cfg0 + r;
    if (cfg >= NCFG) continue;
    float2 v;
    if (cfg < NCFG_REAL) {
      int c = cfg / CPER, q = cfg % CPER;
      int i, b;
      if (q < 196)       { i = 2; b = 0; }
      else if (q < 637)  { i = 3; b = 196; }
      else if (q < 1421) { i = 4; b = 637; }
      else               { i = 5; b = 1421; }
      q -= b;
      int op2_ = q % 7; q /= 7;
      int f2_  = q % i; q /= i;
      int op1_ = q % 7;
      int f1_  = q / 7;
      int cb = c * 384;
      v = s1f[cb + i * 64 + o2];
      float2 A0 = a1f[op1_ * 64 + o2], B0 = s1f[cb + f1_ * 64 + o2];
      float2 A1 = a1f[op2_ * 64 + o2], B1 = s1f[cb + f2_ * 64 + o2];
      v.x += A0.x * B0.x + A1.x * B1.x;
      v.y += A0.y * B0.y + A1.y * B1.y;
    } else {                           // init node pseudo-config (no in-edges)
      int j = cfg - NCFG_REAL, c = j >> 1, i = j & 1;
      v = s1f[c * 384 + i * 64 + o2];
    }
    ((float2*)(wsh + (w * 8 + r) * 128))[o2] =
        make_float2(fmaxf(v.x, 0.f), fmaxf(v.y, 0.f));
  }
  __syncthreads();

  // ---- step 7: tab[cfg] = y1_cfg @ W2 (R10 verbatim; W2 global, L1-hot) ---
  const float* yb = wsh + (w * 8) * 128;
  const float2* W2f = (const float2*)W2;
  float2 acc[8];
  #pragma unroll
  for (int r = 0; r < 8; ++r) acc[r] = make_float2(0.f, 0.f);

  for (int k = 0; k < 128; k += 4) {
    float4 yv[8];
    #pragma unroll
    for (int r = 0; r < 8; ++r)
      yv[r] = *(const float4*)(yb + r * 128 + k);
    #pragma unroll
    for (int j = 0; j < 4; ++j) {
      float2 wv = W2f[(k + j) * 64 + o2];
      #pragma unroll
      for (int r = 0; r < 8; ++r) {
        float y = COMP4(yv[r], j);
        acc[r].x += y * wv.x;
        acc[r].y += y * wv.y;
      }
    }
  }

  float2* tab = (float2*)(ws + WS_TAB);
  #pragma unroll
  for (int r = 0; r < 8; ++r) {
    int cfg = cfg0 + r;
    if (cfg < NCFG) tab[cfg * 64 + o2] = acc[r];
  }
}

__global__ __launch_bounds__(256) void gather_kernel(
    const int* __restrict__ archs, const float* __restrict__ ws,
    float* __restrict__ out)
{
  const int t  = threadIdx.x;
  const int pp = t >> 6;
  const int o2 = t & 63;
  const int P  = blockIdx.x * 4 + pp;
  const int c  = P & 1;

  __shared__ int archsh[64];
  if (t < 64) archsh[t] = archs[blockIdx.x * 64 + t];
  __syncthreads();

  int f[8], op[8];
  #pragma unroll
  for (int e = 0; e < 8; ++e) { f[e] = archsh[pp * 16 + e]; op[e] = archsh[pp * 16 + 8 + e]; }

  const float2* tab = (const float2*)(ws + WS_TAB);
  const float2* a2f = (const float2*)(ws + WS_AT2F);

  float2 S0 = tab[(NCFG_REAL + c * 2 + 0) * 64 + o2];
  float2 S1 = tab[(NCFG_REAL + c * 2 + 1) * 64 + o2];
  float2 S2, S3, S4, S5;
  {
    const int ib[4] = {0, 196, 637, 1421};
    #pragma unroll
    for (int i = 2; i < 6; ++i) {
      int e0 = 2 * (i - 2), e1 = e0 + 1;
      int cid = c * CPER + ib[i - 2] +
                ((f[e0] * 7 + op[e0]) * i + f[e1]) * 7 + op[e1];
      float2 v = tab[cid * 64 + o2];
      if (i == 2) S2 = v; else if (i == 3) S3 = v;
      else if (i == 4) S4 = v; else S5 = v;
    }
  }
  float2 A2[8];
  #pragma unroll
  for (int e = 0; e < 8; ++e) A2[e] = a2f[op[e] * 64 + o2];

  float r0 = S2.x + S3.x + S4.x + S5.x;
  float r1 = S2.y + S3.y + S4.y + S5.y;
  #pragma unroll
  for (int e = 0; e < 8; ++e) {
    int fe = f[e];
    float sx, sy;
    if (fe == 0)      { sx = S0.x; sy = S0.y; }
    else if (fe == 1) { sx = S1.x; sy = S1.y; }
    else if (fe == 2) { sx = S2.x; sy = S2.y; }
    else if (fe == 3) { sx = S3.x; sy = S3.y; }
    else              { sx = S4.x; sy = S4.y; }
    r0 += A2[e].x * sx;
    r1 += A2[e].y * sy;
  }
  ((float2*)out)[P * 64 + o2] = make_float2(r0 * 0.25f, r1 * 0.25f);
}

// ===================== FALLBACK: R9 verbatim (if ws too small) ============
#define FB_S1   0
#define FB_AT1  1536
#define FB_AT2  2432
#define FB_S2I  3328

__global__ __launch_bounds__(512) void precompute_kernel(
    const float* __restrict__ init_emb, const float* __restrict__ other_emb,
    const float* __restrict__ op_embs,  const float* __restrict__ Wx,
    const float* __restrict__ bx,       const float* __restrict__ W1,
    const float* __restrict__ Wa1,      const float* __restrict__ ba1,
    const float* __restrict__ W2,       const float* __restrict__ Wa2,
    const float* __restrict__ ba2,      float* __restrict__ ws)
{
  const int t   = threadIdx.x;
  const int blk = blockIdx.x;
  __shared__ float y0[576];
  __shared__ float s1sh[1536];
  for (int idx = t; idx < 576; idx += 512) {
    int c = idx / 288, i = (idx / 48) % 6, h = idx % 48;
    const float* nptr = (i < 2) ? (init_emb + (c * 2 + i) * 48)
                                : (other_emb + c * 48);
    float acc = bx[h];
    for (int d = 0; d < 48; ++d) acc += nptr[d] * Wx[d * 48 + h];
    y0[idx] = acc;
  }
  __syncthreads();
  for (int idx = t; idx < 1536; idx += 512) {
    int ci = idx >> 7, o = idx & 127;
    const float* yp = y0 + ci * 48;
    float acc = 0.f;
    for (int h = 0; h < 48; ++h) acc += yp[h] * W1[h * 128 + o];
    s1sh[idx] = acc;
    ws[FB_S1 + idx] = acc;
  }
  for (int idx = blk * 112 + t; idx < (blk + 1) * 112; idx += 512) {
    int op = idx >> 7, o = idx & 127;
    float a1 = ba1[o], a2 = ba2[o];
    for (int d = 0; d < 48; ++d) {
      float e = op_embs[op * 48 + d];
      a1 += e * Wa1[d * 128 + o];
      a2 += e * Wa2[d * 128 + o];
    }
    ws[FB_AT1 + idx] = (op == 0) ? 0.f : sigmoidf_(a1);
    ws[FB_AT2 + idx] = (op == 0) ? 0.f : sigmoidf_(a2);
  }
  __syncthreads();
  for (int idx = blk * 64 + t; idx < (blk + 1) * 64; idx += 512) {
    int c = idx >> 8, i = (idx >> 7) & 1, o = idx & 127;
    const float* sp = s1sh + (c * 6 + i) * 128;
    float acc = 0.f;
    for (int h = 0; h < 128; ++h) acc += fmaxf(sp[h], 0.f) * W2[h * 128 + o];
    ws[FB_S2I + idx] = acc;
  }
}

__global__ __launch_bounds__(256) void main_kernel(
    const int* __restrict__ archs, const float* __restrict__ W2,
    const float* __restrict__ ws, float* __restrict__ out)
{
  const int t  = threadIdx.x;
  const int pp = t >> 6;
  const int o2 = t & 63;
  const int P  = blockIdx.x * 4 + pp;
  const int c  = P & 1;
  __shared__ float y1sh[4][512];
  __shared__ int   archsh[64];
  if (t < 64) archsh[t] = archs[blockIdx.x * 64 + t];
  __syncthreads();
  int f[8], op[8];
  #pragma unroll
  for (int e = 0; e < 8; ++e) { f[e] = archsh[pp * 16 + e]; op[e] = archsh[pp * 16 + 8 + e]; }
  const float2* s1p = (const float2*)ws + c * 384;
  const float2* at1 = (const float2*)(ws + FB_AT1);
  const float2* at2 = (const float2*)(ws + FB_AT2);
  const float2* s2i = (const float2*)(ws + FB_S2I) + c * 128;
  float2 A2[8];
  #pragma unroll
  for (int e = 0; e < 8; ++e) A2[e] = at2[op[e] * 64 + o2];
  float2 S0 = s2i[o2], S1 = s2i[64 + o2];
  #pragma unroll
  for (int i = 0; i < 4; ++i) {
    float2 v = s1p[(2 + i) * 64 + o2];
    int e0 = 2 * i, e1 = 2 * i + 1;
    float2 A0 = at1[op[e0] * 64 + o2];
    float2 B0 = s1p[f[e0] * 64 + o2];
    float2 A1 = at1[op[e1] * 64 + o2];
    float2 B1 = s1p[f[e1] * 64 + o2];
    v.x += A0.x * B0.x + A1.x * B1.x;
    v.y += A0.y * B0.y + A1.y * B1.y;
    ((float2*)(y1sh[pp] + i * 128))[o2] =
        make_float2(fmaxf(v.x, 0.f), fmaxf(v.y, 0.f));
  }
  __syncthreads();
  const float* y1p = y1sh[pp];
  const float2* W2f = (const float2*)W2;
  float ax0 = 0, ax1 = 0, ax2 = 0, ax3 = 0;
  float ay0 = 0, ay1 = 0, ay2 = 0, ay3 = 0;
  for (int h = 0; h < 128; h += 4) {
    float4 q0 = *(const float4*)(y1p + 0 * 128 + h);
    float4 q1 = *(const float4*)(y1p + 1 * 128 + h);
    float4 q2 = *(const float4*)(y1p + 2 * 128 + h);
    float4 q3 = *(const float4*)(y1p + 3 * 128 + h);
    #pragma unroll
    for (int j = 0; j < 4; ++j) {
      float2 wf = W2f[(h + j) * 64 + o2];
      float w0 = wf.x, w1 = wf.y, y;
      y = COMP4(q0, j); ax0 += y * w0; ay0 += y * w1;
      y = COMP4(q1, j); ax1 += y * w0; ay1 += y * w1;
      y = COMP4(q2, j); ax2 += y * w0; ay2 += y * w1;
      y = COMP4(q3, j); ax3 += y * w0; ay3 += y * w1;
    }
  }
  float r0 = ax0 + ax1 + ax2 + ax3;
  float r1 = ay0 + ay1 + ay2 + ay3;
  #pragma unroll
  for (int e = 0; e < 8; ++e) {
    int fe = f[e];
    float sx, sy;
    if (fe == 0)      { sx = S0.x; sy = S0.y; }
    else if (fe == 1) { sx = S1.x; sy = S1.y; }
    else if (fe == 2) { sx = ax0; sy = ay0; }
    else if (fe == 3) { sx = ax1; sy = ay1; }
    else if (fe == 4) { sx = ax2; sy = ay2; }
    else              { sx = ax3; sy = ay3; }
    r0 += A2[e].x * sx;
    r1 += A2[e].y * sy;
  }
  ((float2*)out)[P * 64 + o2] = make_float2(r0 * 0.25f, r1 * 0.25f);
}

extern "C" void kernel_launch(void* const* d_in, const int* in_sizes, int n_in,
                              void* d_out, int out_size, void* d_ws, size_t ws_size,
                              hipStream_t stream) {
  const int* archs = (const int*)d_in[0];
  float* ws = (float*)d_ws;
  if (ws_size >= WS_NEED) {
    config_kernel<<<83, 512, 0, stream>>>(
        (const float*)d_in[1], (const float*)d_in[2], (const float*)d_in[3],
        (const float*)d_in[4], (const float*)d_in[5], (const float*)d_in[6],
        (const float*)d_in[7], (const float*)d_in[8], (const float*)d_in[9],
        (const float*)d_in[10], (const float*)d_in[11], ws);
    gather_kernel<<<NPAIR / 4, 256, 0, stream>>>(archs, ws, (float*)d_out);
  } else {
    precompute_kernel<<<8, 512, 0, stream>>>(
        (const float*)d_in[1], (const float*)d_in[2], (const float*)d_in[3],
        (const float*)d_in[4], (const float*)d_in[5], (const float*)d_in[6],
        (const float*)d_in[7], (const float*)d_in[8], (const float*)d_in[9],
        (const float*)d_in[10], (const float*)d_in[11], ws);
    main_kernel<<<NPAIR / 4, 256, 0, stream>>>(archs, (const float*)d_in[9], ws,
                                               (float*)d_out);
  }
}